// Round 2
// baseline (4244.592 us; speedup 1.0000x reference)
//
#include <hip/hip_runtime.h>
#include <hip/hip_bf16.h>
#include <cstdint>
#include <cstddef>

typedef __bf16 bf16;
typedef bf16 bf16x8 __attribute__((ext_vector_type(8)));
typedef bf16 bf16x4 __attribute__((ext_vector_type(4)));
typedef float f32x4 __attribute__((ext_vector_type(4)));
typedef unsigned int u32;

#define GLD_LDS16(gptr, lptr)                                                        \
  __builtin_amdgcn_global_load_lds((const __attribute__((address_space(1))) u32*)(gptr), \
                                   (__attribute__((address_space(3))) u32*)(lptr), 16, 0, 0)

static constexpr int S = 36, D = 768, H = 12, HD = 64, DFF = 1536;
static constexpr int BC = 1536;        // B*C images
static constexpr int M = BC * S;       // 55296 tokens
static constexpr int OUTD = 256;

// ---------------------------------------------------------------- fp32 -> bf16
__global__ __launch_bounds__(256) void f2b_kernel(const float* __restrict__ in,
                                                  bf16* __restrict__ out, int n4) {
  int i = blockIdx.x * 256 + threadIdx.x;
  if (i < n4) {
    float4 f = ((const float4*)in)[i];
    bf16x4 o = {(bf16)f.x, (bf16)f.y, (bf16)f.z, (bf16)f.w};
    ((bf16x4*)out)[i] = o;
  }
}

// ---------------------------------------------------------------- patch embed
__global__ __launch_bounds__(256) void patch_embed(const float* __restrict__ batch,
                                                   const float* __restrict__ Wp,
                                                   const float* __restrict__ bp,
                                                   const float* __restrict__ pos,
                                                   float* __restrict__ z) {
  int dblk = blockIdx.x;           // 0..2
  int tok = blockIdx.y;            // 0..55295
  int tid = threadIdx.x;
  int bc = tok / S, s = tok % S;
  int pr = s / 6, pc = s % 6;
  __shared__ float patch[36];
  if (tid < 36) {
    int i = tid / 6, j = tid % 6;
    patch[tid] = batch[((size_t)bc * 36 + pr * 6 + i) * 36 + pc * 6 + j];
  }
  __syncthreads();
  int d = dblk * 256 + tid;
  float acc = 0.f;
#pragma unroll
  for (int k = 0; k < 36; ++k) acc += patch[k] * Wp[d * 36 + k];
  z[(size_t)tok * D + d] = acc + bp[d] + pos[s * D + d];
}

// ---------------------------------------------------------------- LN stats (mean, rstd) per row
__global__ __launch_bounds__(256) void ln_stats(const float* __restrict__ zin,
                                                float* __restrict__ stats) {
  int row = blockIdx.x * 4 + (threadIdx.x >> 6);
  int lane = threadIdx.x & 63;
  const float* zr = zin + (size_t)row * D;
  float x[12];
#pragma unroll
  for (int i = 0; i < 12; ++i) x[i] = zr[i * 64 + lane];
  float s = 0.f;
#pragma unroll
  for (int i = 0; i < 12; ++i) s += x[i];
#pragma unroll
  for (int off = 32; off >= 1; off >>= 1) s += __shfl_xor(s, off, 64);
  float m = s * (1.f / 768.f);
  float v = 0.f;
#pragma unroll
  for (int i = 0; i < 12; ++i) { float dd = x[i] - m; v += dd * dd; }
#pragma unroll
  for (int off = 32; off >= 1; off >>= 1) v += __shfl_xor(v, off, 64);
  v *= (1.f / 768.f);
  if (lane == 0) {
    stats[(size_t)row * 2] = m;
    stats[(size_t)row * 2 + 1] = rsqrtf(v + 1e-5f);
  }
}

// ---------------------------------------------------------------- LN in-place (fp32)
__global__ __launch_bounds__(256) void ln_inplace(float* __restrict__ z,
                                                  const float* __restrict__ g,
                                                  const float* __restrict__ bt) {
  int row = blockIdx.x * 4 + (threadIdx.x >> 6);
  int lane = threadIdx.x & 63;
  float* zr = z + (size_t)row * D;
  float x[12];
#pragma unroll
  for (int i = 0; i < 12; ++i) x[i] = zr[i * 64 + lane];
  float s = 0.f;
#pragma unroll
  for (int i = 0; i < 12; ++i) s += x[i];
#pragma unroll
  for (int off = 32; off >= 1; off >>= 1) s += __shfl_xor(s, off, 64);
  float m = s * (1.f / 768.f);
  float v = 0.f;
#pragma unroll
  for (int i = 0; i < 12; ++i) { float dd = x[i] - m; v += dd * dd; }
#pragma unroll
  for (int off = 32; off >= 1; off >>= 1) v += __shfl_xor(v, off, 64);
  v *= (1.f / 768.f);
  float rstd = rsqrtf(v + 1e-5f);
#pragma unroll
  for (int i = 0; i < 12; ++i) {
    int d = i * 64 + lane;
    zr[d] = (x[i] - m) * rstd * g[d] + bt[d];
  }
}

// ---------------------------------------------------------------- fused attention
// one wave per (head, image): LN1 on the fly + QKV proj + scores + softmax + AV; z += o
__global__ __launch_bounds__(64) void attn_kernel(const float* __restrict__ zg,
                                                  const float* __restrict__ stats,
                                                  const float* __restrict__ g1,
                                                  const float* __restrict__ b1_,
                                                  const bf16* __restrict__ Wq,
                                                  const bf16* __restrict__ Wk,
                                                  const bf16* __restrict__ Wv,
                                                  const float* __restrict__ bq,
                                                  const float* __restrict__ bk,
                                                  const float* __restrict__ bv,
                                                  float* __restrict__ z) {
  int head = blockIdx.x;
  int bc = blockIdx.y;
  __shared__ __align__(16) bf16 hbuf[48 * 64];
  __shared__ __align__(16) bf16 qbuf[48 * 64];
  __shared__ __align__(16) bf16 kbuf[48 * 64];
  __shared__ __align__(16) bf16 vt[64 * 64];   // vt[e][t]
  __shared__ __align__(16) bf16 pbuf[48 * 64];
  int lane = threadIdx.x;
  int lr = lane & 15, quad = lane >> 4;

  // zero pads
  for (int s2 = 36; s2 < 48; ++s2) hbuf[s2 * 64 + lane] = (bf16)0.f;
  for (int i = lane; i < 64 * 16; i += 64) { int e = i >> 4, t = 48 + (i & 15); vt[e * 64 + t] = (bf16)0.f; }
  for (int i = lane; i < 48 * 16; i += 64) { int s2 = i >> 4, t = 48 + (i & 15); pbuf[s2 * 64 + t] = (bf16)0.f; }
  // load z slice (36 x 64), normalize with precomputed stats
  const float* zsrc = zg + ((size_t)bc * S) * D + head * HD;
  const float* st = stats + (size_t)bc * S * 2;
  float gv = g1[head * HD + lane], bvv = b1_[head * HD + lane];
  for (int s2 = 0; s2 < 36; ++s2) {
    float mm = st[s2 * 2], rr = st[s2 * 2 + 1];
    hbuf[s2 * 64 + lane] = (bf16)((zsrc[(size_t)s2 * D + lane] - mm) * rr * gv + bvv);
  }
  __syncthreads();

  // ---- projections q,k,v
  const bf16* Wm[3] = {Wq + (size_t)head * 4096, Wk + (size_t)head * 4096, Wv + (size_t)head * 4096};
  const float* Bm[3] = {bq + head * 64, bk + head * 64, bv + head * 64};
  for (int p = 0; p < 3; ++p) {
    bf16x8 bfr[4][2];
#pragma unroll
    for (int nt = 0; nt < 4; ++nt)
#pragma unroll
      for (int kt = 0; kt < 2; ++kt)
        bfr[nt][kt] = *(const bf16x8*)(Wm[p] + (nt * 16 + lr) * 64 + kt * 32 + quad * 8);
#pragma unroll
    for (int mt = 0; mt < 3; ++mt) {
      f32x4 acc[4] = {};
#pragma unroll
      for (int kt = 0; kt < 2; ++kt) {
        bf16x8 a = *(const bf16x8*)&hbuf[(mt * 16 + lr) * 64 + kt * 32 + quad * 8];
#pragma unroll
        for (int nt = 0; nt < 4; ++nt)
          acc[nt] = __builtin_amdgcn_mfma_f32_16x16x32_bf16(a, bfr[nt][kt], acc[nt], 0, 0, 0);
      }
#pragma unroll
      for (int nt = 0; nt < 4; ++nt) {
        float bb = Bm[p][nt * 16 + lr];
#pragma unroll
        for (int r = 0; r < 4; ++r) {
          int s2 = mt * 16 + quad * 4 + r;
          int e = nt * 16 + lr;
          float val = acc[nt][r] + bb;
          if (p == 0) qbuf[s2 * 64 + e] = (bf16)val;
          else if (p == 1) kbuf[s2 * 64 + e] = (bf16)val;
          else vt[e * 64 + s2] = (bf16)val;
        }
      }
    }
  }
  __syncthreads();

  // ---- scores + softmax
  f32x4 sc[3][3];
#pragma unroll
  for (int mt = 0; mt < 3; ++mt)
#pragma unroll
    for (int nt = 0; nt < 3; ++nt) {
      f32x4 a = {};
#pragma unroll
      for (int kt = 0; kt < 2; ++kt) {
        bf16x8 af = *(const bf16x8*)&qbuf[(mt * 16 + lr) * 64 + kt * 32 + quad * 8];
        bf16x8 bf_ = *(const bf16x8*)&kbuf[(nt * 16 + lr) * 64 + kt * 32 + quad * 8];
        a = __builtin_amdgcn_mfma_f32_16x16x32_bf16(af, bf_, a, 0, 0, 0);
      }
      int t = nt * 16 + lr;
#pragma unroll
      for (int r = 0; r < 4; ++r) {
        float v = a[r] * 0.125f;     // 1/sqrt(64)
        if (t >= 36) v = -1e30f;
        sc[mt][nt][r] = v;
      }
    }
#pragma unroll
  for (int mt = 0; mt < 3; ++mt) {
    float mx[4], sum[4];
#pragma unroll
    for (int r = 0; r < 4; ++r)
      mx[r] = fmaxf(fmaxf(sc[mt][0][r], sc[mt][1][r]), sc[mt][2][r]);
#pragma unroll
    for (int r = 0; r < 4; ++r)
#pragma unroll
      for (int off = 8; off >= 1; off >>= 1) mx[r] = fmaxf(mx[r], __shfl_xor(mx[r], off, 64));
#pragma unroll
    for (int r = 0; r < 4; ++r) sum[r] = 0.f;
#pragma unroll
    for (int nt = 0; nt < 3; ++nt)
#pragma unroll
      for (int r = 0; r < 4; ++r) {
        float e = __expf(sc[mt][nt][r] - mx[r]);
        sc[mt][nt][r] = e;
        sum[r] += e;
      }
#pragma unroll
    for (int r = 0; r < 4; ++r)
#pragma unroll
      for (int off = 8; off >= 1; off >>= 1) sum[r] += __shfl_xor(sum[r], off, 64);
#pragma unroll
    for (int nt = 0; nt < 3; ++nt)
#pragma unroll
      for (int r = 0; r < 4; ++r) {
        int s2 = mt * 16 + quad * 4 + r;
        int t = nt * 16 + lr;
        pbuf[s2 * 64 + t] = (bf16)(sc[mt][nt][r] / sum[r]);
      }
  }
  __syncthreads();

  // ---- o = p @ v, z += o
#pragma unroll
  for (int mt = 0; mt < 3; ++mt) {
    f32x4 o[4] = {};
#pragma unroll
    for (int kt = 0; kt < 2; ++kt) {
      bf16x8 a = *(const bf16x8*)&pbuf[(mt * 16 + lr) * 64 + kt * 32 + quad * 8];
#pragma unroll
      for (int nt = 0; nt < 4; ++nt) {
        bf16x8 b = *(const bf16x8*)&vt[(nt * 16 + lr) * 64 + kt * 32 + quad * 8];
        o[nt] = __builtin_amdgcn_mfma_f32_16x16x32_bf16(a, b, o[nt], 0, 0, 0);
      }
    }
#pragma unroll
    for (int nt = 0; nt < 4; ++nt)
#pragma unroll
      for (int r = 0; r < 4; ++r) {
        int s2 = mt * 16 + quad * 4 + r;
        if (s2 < 36) {
          int e = nt * 16 + lr;
          size_t idx = ((size_t)bc * S + s2) * D + head * HD + e;
          z[idx] += o[nt][r];
        }
      }
  }
}

// ---------------------------------------------------------------- GEMM (B^T layout)
// C[m,n] = sum_k A[m,k]*B[n,k]
// MODE 0: bf16 out = relu(.+bias); MODE 1: f32 out = .+bias+res; MODE 2: f32 out = .+bias
// AF32 1: A is fp32, staged via VGPR+convert; 0: A bf16 via global_load_lds
template <int N, int K, int MODE, int AF32>
__global__ __launch_bounds__(256) void gemm_bt(const void* __restrict__ A,
                                               const bf16* __restrict__ Bw,
                                               const float* __restrict__ bias,
                                               const float* __restrict__ res,
                                               void* __restrict__ outp) {
  constexpr int BK = 64;
  __shared__ __align__(16) bf16 As[128 * BK];
  __shared__ __align__(16) bf16 Bs[128 * BK];
  int tid = threadIdx.x;
  int bn = blockIdx.x, bm = blockIdx.y;
  const bf16* Abf = (const bf16*)A + (size_t)bm * 128 * K;
  const float* Af = (const float*)A + (size_t)bm * 128 * K;
  const bf16* Bb = Bw + (size_t)bn * 128 * K;
  int lane = tid & 63, wave = tid >> 6;
  int wm = (wave >> 1) * 64, wn = (wave & 1) * 64;
  int lr = lane & 15, quad = lane >> 4;
  f32x4 acc[4][4] = {};
  for (int k0 = 0; k0 < K; k0 += BK) {
    if (AF32) {
#pragma unroll
      for (int r = 0; r < 8; ++r) {
        int c = r * 256 + tid;            // 0..2047 float4-units
        int row = c >> 4, col4 = (c & 15) * 4;
        float4 f = *(const float4*)(Af + (size_t)row * K + k0 + col4);
        bf16x4 o = {(bf16)f.x, (bf16)f.y, (bf16)f.z, (bf16)f.w};
        *(bf16x4*)&As[row * BK + col4] = o;
      }
    } else {
#pragma unroll
      for (int r = 0; r < 4; ++r) {
        int c = r * 256 + tid;
        int row = c >> 3, col = (c & 7) * 8;
        GLD_LDS16(Abf + (size_t)row * K + k0 + col, &As[c * 8]);
      }
    }
#pragma unroll
    for (int r = 0; r < 4; ++r) {
      int c = r * 256 + tid;
      int row = c >> 3, col = (c & 7) * 8;
      GLD_LDS16(Bb + (size_t)row * K + k0 + col, &Bs[c * 8]);
    }
    __syncthreads();
#pragma unroll
    for (int kt = 0; kt < 2; ++kt) {
      bf16x8 af[4], bfr[4];
#pragma unroll
      for (int mt = 0; mt < 4; ++mt) af[mt] = *(const bf16x8*)&As[(wm + mt * 16 + lr) * BK + kt * 32 + quad * 8];
#pragma unroll
      for (int nt = 0; nt < 4; ++nt) bfr[nt] = *(const bf16x8*)&Bs[(wn + nt * 16 + lr) * BK + kt * 32 + quad * 8];
#pragma unroll
      for (int mt = 0; mt < 4; ++mt)
#pragma unroll
        for (int nt = 0; nt < 4; ++nt)
          acc[mt][nt] = __builtin_amdgcn_mfma_f32_16x16x32_bf16(af[mt], bfr[nt], acc[mt][nt], 0, 0, 0);
    }
    __syncthreads();
  }
  int row0 = bm * 128 + wm + quad * 4;
  int col0 = bn * 128 + wn + lr;
#pragma unroll
  for (int mt = 0; mt < 4; ++mt)
#pragma unroll
    for (int nt = 0; nt < 4; ++nt) {
      int col = col0 + nt * 16;
      float bv = bias[col];
#pragma unroll
      for (int r = 0; r < 4; ++r) {
        size_t idx = (size_t)(row0 + mt * 16 + r) * N + col;
        float v = acc[mt][nt][r] + bv;
        if (MODE == 0) ((bf16*)outp)[idx] = (bf16)fmaxf(v, 0.f);
        else if (MODE == 1) ((float*)outp)[idx] = v + res[idx];
        else ((float*)outp)[idx] = v;
      }
    }
}

// ---------------------------------------------------------------- launch
extern "C" void kernel_launch(void* const* d_in, const int* in_sizes, int n_in,
                              void* d_out, int out_size, void* d_ws, size_t ws_size,
                              hipStream_t stream) {
  const float* batch   = (const float*)d_in[0];
  const float* W_patch = (const float*)d_in[1];
  const float* b_patch = (const float*)d_in[2];
  const float* pos     = (const float*)d_in[3];
  const float* ln1_g   = (const float*)d_in[4];
  const float* ln1_b   = (const float*)d_in[5];
  const float* Wq      = (const float*)d_in[6];
  const float* bq      = (const float*)d_in[7];
  const float* Wk      = (const float*)d_in[8];
  const float* bk      = (const float*)d_in[9];
  const float* Wv      = (const float*)d_in[10];
  const float* bv      = (const float*)d_in[11];
  const float* ln2_g   = (const float*)d_in[12];
  const float* ln2_b   = (const float*)d_in[13];
  const float* W1      = (const float*)d_in[14];
  const float* b1      = (const float*)d_in[15];
  const float* W2      = (const float*)d_in[16];
  const float* b2      = (const float*)d_in[17];
  const float* W_out   = (const float*)d_in[18];
  const float* b_out   = (const float*)d_in[19];
  float* out = (float*)d_out;

  char* ws = (char*)d_ws;
  size_t off = 0;
  float* z     = (float*)(ws + off); off += (size_t)M * D * 4;        // 169,869,312
  float* stats = (float*)(ws + off); off += (size_t)M * 2 * 4;        // 442,368
  bf16* wq_b = (bf16*)(ws + off);    off += (size_t)4 * H * 4096 * 2; // 393,216
  bf16* wk_b = (bf16*)(ws + off);    off += (size_t)4 * H * 4096 * 2;
  bf16* wv_b = (bf16*)(ws + off);    off += (size_t)4 * H * 4096 * 2;
  bf16* w1_b = (bf16*)(ws + off);    off += (size_t)4 * DFF * D * 2;  // 9,437,184
  bf16* w2_b = (bf16*)(ws + off);    off += (size_t)4 * D * DFF * 2;
  bf16* wo_b = (bf16*)(ws + off);    off += (size_t)OUTD * D * 2;     // 393,216
  bf16* act  = (bf16*)(ws + off);    // remainder, chunked

  // rows-per-chunk for the MLP, from remaining workspace (multiple of 128)
  size_t avail = ws_size > off ? ws_size - off : (size_t)0;
  long long rcl = (long long)(avail / ((size_t)DFF * 2));
  int rc = (rcl > (long long)M) ? M : (int)rcl;
  rc = (rc / 128) * 128;
  if (rc <= 0) rc = 128;   // last resort; avoids div-by-zero

  // weight conversion (fp32 -> bf16); n4 = float4 count
  f2b_kernel<<<192, 256, 0, stream>>>(Wq, wq_b, 49152);
  f2b_kernel<<<192, 256, 0, stream>>>(Wk, wk_b, 49152);
  f2b_kernel<<<192, 256, 0, stream>>>(Wv, wv_b, 49152);
  f2b_kernel<<<4608, 256, 0, stream>>>(W1, w1_b, 1179648);
  f2b_kernel<<<4608, 256, 0, stream>>>(W2, w2_b, 1179648);
  f2b_kernel<<<192, 256, 0, stream>>>(W_out, wo_b, 49152);

  patch_embed<<<dim3(3, M), 256, 0, stream>>>(batch, W_patch, b_patch, pos, z);

  for (int l = 0; l < 4; ++l) {
    ln_stats<<<M / 4, 256, 0, stream>>>(z, stats);
    attn_kernel<<<dim3(H, BC), 64, 0, stream>>>(z, stats, ln1_g + l * D, ln1_b + l * D,
        wq_b + (size_t)l * H * 4096, wk_b + (size_t)l * H * 4096, wv_b + (size_t)l * H * 4096,
        bq + l * H * 64, bk + l * H * 64, bv + l * H * 64, z);
    ln_inplace<<<M / 4, 256, 0, stream>>>(z, ln2_g + l * D, ln2_b + l * D);
    for (int m0 = 0; m0 < M; m0 += rc) {
      int mr = (M - m0 < rc) ? (M - m0) : rc;
      gemm_bt<DFF, D, 0, 1><<<dim3(DFF / 128, mr / 128), 256, 0, stream>>>(
          z + (size_t)m0 * D, w1_b + (size_t)l * DFF * D, b1 + l * DFF, nullptr, act);
      gemm_bt<D, DFF, 1, 0><<<dim3(D / 128, mr / 128), 256, 0, stream>>>(
          act, w2_b + (size_t)l * D * DFF, b2 + l * D, z + (size_t)m0 * D, z + (size_t)m0 * D);
    }
  }

  gemm_bt<OUTD, D, 2, 1><<<dim3(OUTD / 128, M / 128), 256, 0, stream>>>(
      z, wo_b, b_out, nullptr, out);
}

// Round 5
// 4018.873 us; speedup vs baseline: 1.0562x; 1.0562x over previous
//
#include <hip/hip_runtime.h>
#include <hip/hip_bf16.h>
#include <cstdint>
#include <cstddef>

typedef __bf16 bf16;
typedef bf16 bf16x8 __attribute__((ext_vector_type(8)));
typedef bf16 bf16x4 __attribute__((ext_vector_type(4)));
typedef float f32x4 __attribute__((ext_vector_type(4)));
typedef unsigned int u32;

#define GLD_LDS16(gptr, lptr)                                                        \
  __builtin_amdgcn_global_load_lds((const __attribute__((address_space(1))) u32*)(gptr), \
                                   (__attribute__((address_space(3))) u32*)(lptr), 16, 0, 0)

static constexpr int S = 36, D = 768, H = 12, HD = 64, DFF = 1536;
static constexpr int BC = 1536;        // B*C images
static constexpr int M = BC * S;       // 55296 tokens
static constexpr int OUTD = 256;

// ---------------------------------------------------------------- fp32 -> bf16
__global__ __launch_bounds__(256) void f2b_kernel(const float* __restrict__ in,
                                                  bf16* __restrict__ out, int n4) {
  int i = blockIdx.x * 256 + threadIdx.x;
  if (i < n4) {
    float4 f = ((const float4*)in)[i];
    bf16x4 o = {(bf16)f.x, (bf16)f.y, (bf16)f.z, (bf16)f.w};
    ((bf16x4*)out)[i] = o;
  }
}

// ---------------------------------------------------------------- patch embed (NEW in R5)
// one block per image; patch in LDS (broadcast reads), Wp row in registers.
// Numerically identical to R2's version (same ascending-k fp32 accumulation).
__global__ __launch_bounds__(256) void patch_embed(const float* __restrict__ batch,
                                                   const float* __restrict__ Wp,
                                                   const float* __restrict__ bp,
                                                   const float* __restrict__ pos,
                                                   float* __restrict__ z) {
  int bc = blockIdx.x, tid = threadIdx.x;
  __shared__ float p[36][40];          // [token][pixel], padded row
  for (int i = tid; i < 1296; i += 256) {
    float f = batch[(size_t)bc * 1296 + i];
    int row = i / 36, col = i - row * 36;
    p[(row / 6) * 6 + col / 6][(row % 6) * 6 + (col % 6)] = f;
  }
  __syncthreads();
  for (int c0 = 0; c0 < 768; c0 += 256) {
    int d = c0 + tid;
    float wr[36];
    const float4* wp4 = (const float4*)(Wp + (size_t)d * 36);   // 144B rows, 16B aligned
#pragma unroll
    for (int q = 0; q < 9; ++q) {
      float4 f = wp4[q];
      wr[q * 4] = f.x; wr[q * 4 + 1] = f.y; wr[q * 4 + 2] = f.z; wr[q * 4 + 3] = f.w;
    }
    float gb = bp[d];
    for (int s = 0; s < 36; ++s) {
      float acc = 0.f;
#pragma unroll
      for (int k = 0; k < 36; ++k) acc += p[s][k] * wr[k];
      z[((size_t)bc * 36 + s) * 768 + d] = acc + gb + pos[s * 768 + d];
    }
  }
}

// ---------------------------------------------------------------- LN stats (mean, rstd) per row
__global__ __launch_bounds__(256) void ln_stats(const float* __restrict__ zin,
                                                float* __restrict__ stats) {
  int row = blockIdx.x * 4 + (threadIdx.x >> 6);
  int lane = threadIdx.x & 63;
  const float* zr = zin + (size_t)row * D;
  float x[12];
#pragma unroll
  for (int i = 0; i < 12; ++i) x[i] = zr[i * 64 + lane];
  float s = 0.f;
#pragma unroll
  for (int i = 0; i < 12; ++i) s += x[i];
#pragma unroll
  for (int off = 32; off >= 1; off >>= 1) s += __shfl_xor(s, off, 64);
  float m = s * (1.f / 768.f);
  float v = 0.f;
#pragma unroll
  for (int i = 0; i < 12; ++i) { float dd = x[i] - m; v += dd * dd; }
#pragma unroll
  for (int off = 32; off >= 1; off >>= 1) v += __shfl_xor(v, off, 64);
  v *= (1.f / 768.f);
  if (lane == 0) {
    stats[(size_t)row * 2] = m;
    stats[(size_t)row * 2 + 1] = rsqrtf(v + 1e-5f);
  }
}

// ---------------------------------------------------------------- LN in-place (fp32)
__global__ __launch_bounds__(256) void ln_inplace(float* __restrict__ z,
                                                  const float* __restrict__ g,
                                                  const float* __restrict__ bt) {
  int row = blockIdx.x * 4 + (threadIdx.x >> 6);
  int lane = threadIdx.x & 63;
  float* zr = z + (size_t)row * D;
  float x[12];
#pragma unroll
  for (int i = 0; i < 12; ++i) x[i] = zr[i * 64 + lane];
  float s = 0.f;
#pragma unroll
  for (int i = 0; i < 12; ++i) s += x[i];
#pragma unroll
  for (int off = 32; off >= 1; off >>= 1) s += __shfl_xor(s, off, 64);
  float m = s * (1.f / 768.f);
  float v = 0.f;
#pragma unroll
  for (int i = 0; i < 12; ++i) { float dd = x[i] - m; v += dd * dd; }
#pragma unroll
  for (int off = 32; off >= 1; off >>= 1) v += __shfl_xor(v, off, 64);
  v *= (1.f / 768.f);
  float rstd = rsqrtf(v + 1e-5f);
#pragma unroll
  for (int i = 0; i < 12; ++i) {
    int d = i * 64 + lane;
    zr[d] = (x[i] - m) * rstd * g[d] + bt[d];
  }
}

// ---------------------------------------------------------------- fused attention
// one wave per (head, image): LN1 on the fly (stats precomputed) + QKV proj +
// scores + softmax + AV; z += o   (R2-verbatim)
__global__ __launch_bounds__(64) void attn_kernel(const float* __restrict__ zg,
                                                  const float* __restrict__ stats,
                                                  const float* __restrict__ g1,
                                                  const float* __restrict__ b1_,
                                                  const bf16* __restrict__ Wq,
                                                  const bf16* __restrict__ Wk,
                                                  const bf16* __restrict__ Wv,
                                                  const float* __restrict__ bq,
                                                  const float* __restrict__ bk,
                                                  const float* __restrict__ bv,
                                                  float* __restrict__ z) {
  int head = blockIdx.x;
  int bc = blockIdx.y;
  __shared__ __align__(16) bf16 hbuf[48 * 64];
  __shared__ __align__(16) bf16 qbuf[48 * 64];
  __shared__ __align__(16) bf16 kbuf[48 * 64];
  __shared__ __align__(16) bf16 vt[64 * 64];   // vt[e][t]
  __shared__ __align__(16) bf16 pbuf[48 * 64];
  int lane = threadIdx.x;
  int lr = lane & 15, quad = lane >> 4;

  // zero pads
  for (int s2 = 36; s2 < 48; ++s2) hbuf[s2 * 64 + lane] = (bf16)0.f;
  for (int i = lane; i < 64 * 16; i += 64) { int e = i >> 4, t = 48 + (i & 15); vt[e * 64 + t] = (bf16)0.f; }
  for (int i = lane; i < 48 * 16; i += 64) { int s2 = i >> 4, t = 48 + (i & 15); pbuf[s2 * 64 + t] = (bf16)0.f; }
  // load z slice (36 x 64), normalize with precomputed stats
  const float* zsrc = zg + ((size_t)bc * S) * D + head * HD;
  const float* st = stats + (size_t)bc * S * 2;
  float gv = g1[head * HD + lane], bvv = b1_[head * HD + lane];
  for (int s2 = 0; s2 < 36; ++s2) {
    float mm = st[s2 * 2], rr = st[s2 * 2 + 1];
    hbuf[s2 * 64 + lane] = (bf16)((zsrc[(size_t)s2 * D + lane] - mm) * rr * gv + bvv);
  }
  __syncthreads();

  // ---- projections q,k,v
  const bf16* Wm[3] = {Wq + (size_t)head * 4096, Wk + (size_t)head * 4096, Wv + (size_t)head * 4096};
  const float* Bm[3] = {bq + head * 64, bk + head * 64, bv + head * 64};
  for (int p = 0; p < 3; ++p) {
    bf16x8 bfr[4][2];
#pragma unroll
    for (int nt = 0; nt < 4; ++nt)
#pragma unroll
      for (int kt = 0; kt < 2; ++kt)
        bfr[nt][kt] = *(const bf16x8*)(Wm[p] + (nt * 16 + lr) * 64 + kt * 32 + quad * 8);
#pragma unroll
    for (int mt = 0; mt < 3; ++mt) {
      f32x4 acc[4] = {};
#pragma unroll
      for (int kt = 0; kt < 2; ++kt) {
        bf16x8 a = *(const bf16x8*)&hbuf[(mt * 16 + lr) * 64 + kt * 32 + quad * 8];
#pragma unroll
        for (int nt = 0; nt < 4; ++nt)
          acc[nt] = __builtin_amdgcn_mfma_f32_16x16x32_bf16(a, bfr[nt][kt], acc[nt], 0, 0, 0);
      }
#pragma unroll
      for (int nt = 0; nt < 4; ++nt) {
        float bb = Bm[p][nt * 16 + lr];
#pragma unroll
        for (int r = 0; r < 4; ++r) {
          int s2 = mt * 16 + quad * 4 + r;
          int e = nt * 16 + lr;
          float val = acc[nt][r] + bb;
          if (p == 0) qbuf[s2 * 64 + e] = (bf16)val;
          else if (p == 1) kbuf[s2 * 64 + e] = (bf16)val;
          else vt[e * 64 + s2] = (bf16)val;
        }
      }
    }
  }
  __syncthreads();

  // ---- scores + softmax
  f32x4 sc[3][3];
#pragma unroll
  for (int mt = 0; mt < 3; ++mt)
#pragma unroll
    for (int nt = 0; nt < 3; ++nt) {
      f32x4 a = {};
#pragma unroll
      for (int kt = 0; kt < 2; ++kt) {
        bf16x8 af = *(const bf16x8*)&qbuf[(mt * 16 + lr) * 64 + kt * 32 + quad * 8];
        bf16x8 bf_ = *(const bf16x8*)&kbuf[(nt * 16 + lr) * 64 + kt * 32 + quad * 8];
        a = __builtin_amdgcn_mfma_f32_16x16x32_bf16(af, bf_, a, 0, 0, 0);
      }
      int t = nt * 16 + lr;
#pragma unroll
      for (int r = 0; r < 4; ++r) {
        float v = a[r] * 0.125f;     // 1/sqrt(64)
        if (t >= 36) v = -1e30f;
        sc[mt][nt][r] = v;
      }
    }
#pragma unroll
  for (int mt = 0; mt < 3; ++mt) {
    float mx[4], sum[4];
#pragma unroll
    for (int r = 0; r < 4; ++r)
      mx[r] = fmaxf(fmaxf(sc[mt][0][r], sc[mt][1][r]), sc[mt][2][r]);
#pragma unroll
    for (int r = 0; r < 4; ++r)
#pragma unroll
      for (int off = 8; off >= 1; off >>= 1) mx[r] = fmaxf(mx[r], __shfl_xor(mx[r], off, 64));
#pragma unroll
    for (int r = 0; r < 4; ++r) sum[r] = 0.f;
#pragma unroll
    for (int nt = 0; nt < 3; ++nt)
#pragma unroll
      for (int r = 0; r < 4; ++r) {
        float e = __expf(sc[mt][nt][r] - mx[r]);
        sc[mt][nt][r] = e;
        sum[r] += e;
      }
#pragma unroll
    for (int r = 0; r < 4; ++r)
#pragma unroll
      for (int off = 8; off >= 1; off >>= 1) sum[r] += __shfl_xor(sum[r], off, 64);
#pragma unroll
    for (int nt = 0; nt < 3; ++nt)
#pragma unroll
      for (int r = 0; r < 4; ++r) {
        int s2 = mt * 16 + quad * 4 + r;
        int t = nt * 16 + lr;
        pbuf[s2 * 64 + t] = (bf16)(sc[mt][nt][r] / sum[r]);
      }
  }
  __syncthreads();

  // ---- o = p @ v, z += o
#pragma unroll
  for (int mt = 0; mt < 3; ++mt) {
    f32x4 o[4] = {};
#pragma unroll
    for (int kt = 0; kt < 2; ++kt) {
      bf16x8 a = *(const bf16x8*)&pbuf[(mt * 16 + lr) * 64 + kt * 32 + quad * 8];
#pragma unroll
      for (int nt = 0; nt < 4; ++nt) {
        bf16x8 b = *(const bf16x8*)&vt[(nt * 16 + lr) * 64 + kt * 32 + quad * 8];
        o[nt] = __builtin_amdgcn_mfma_f32_16x16x32_bf16(a, b, o[nt], 0, 0, 0);
      }
    }
#pragma unroll
    for (int nt = 0; nt < 4; ++nt)
#pragma unroll
      for (int r = 0; r < 4; ++r) {
        int s2 = mt * 16 + quad * 4 + r;
        if (s2 < 36) {
          int e = nt * 16 + lr;
          size_t idx = ((size_t)bc * S + s2) * D + head * HD + e;
          z[idx] += o[nt][r];
        }
      }
  }
}

// ---------------------------------------------------------------- GEMM (B^T layout)
// C[m,n] = sum_k A[m,k]*B[n,k]
// MODE 0: bf16 out = relu(.+bias); MODE 1: f32 out = .+bias+res; MODE 2: f32 out = .+bias
// AF32 1: A is fp32, staged via VGPR+convert; 0: A bf16 via global_load_lds
template <int N, int K, int MODE, int AF32>
__global__ __launch_bounds__(256) void gemm_bt(const void* __restrict__ A,
                                               const bf16* __restrict__ Bw,
                                               const float* __restrict__ bias,
                                               const float* __restrict__ res,
                                               void* __restrict__ outp) {
  constexpr int BK = 64;
  __shared__ __align__(16) bf16 As[128 * BK];
  __shared__ __align__(16) bf16 Bs[128 * BK];
  int tid = threadIdx.x;
  int bn = blockIdx.x, bm = blockIdx.y;
  const bf16* Abf = (const bf16*)A + (size_t)bm * 128 * K;
  const float* Af = (const float*)A + (size_t)bm * 128 * K;
  const bf16* Bb = Bw + (size_t)bn * 128 * K;
  int lane = tid & 63, wave = tid >> 6;
  int wm = (wave >> 1) * 64, wn = (wave & 1) * 64;
  int lr = lane & 15, quad = lane >> 4;
  f32x4 acc[4][4] = {};
  for (int k0 = 0; k0 < K; k0 += BK) {
    if (AF32) {
#pragma unroll
      for (int r = 0; r < 8; ++r) {
        int c = r * 256 + tid;            // 0..2047 float4-units
        int row = c >> 4, col4 = (c & 15) * 4;
        float4 f = *(const float4*)(Af + (size_t)row * K + k0 + col4);
        bf16x4 o = {(bf16)f.x, (bf16)f.y, (bf16)f.z, (bf16)f.w};
        *(bf16x4*)&As[row * BK + col4] = o;
      }
    } else {
#pragma unroll
      for (int r = 0; r < 4; ++r) {
        int c = r * 256 + tid;
        int row = c >> 3, col = (c & 7) * 8;
        GLD_LDS16(Abf + (size_t)row * K + k0 + col, &As[c * 8]);
      }
    }
#pragma unroll
    for (int r = 0; r < 4; ++r) {
      int c = r * 256 + tid;
      int row = c >> 3, col = (c & 7) * 8;
      GLD_LDS16(Bb + (size_t)row * K + k0 + col, &Bs[c * 8]);
    }
    __syncthreads();
#pragma unroll
    for (int kt = 0; kt < 2; ++kt) {
      bf16x8 af[4], bfr[4];
#pragma unroll
      for (int mt = 0; mt < 4; ++mt) af[mt] = *(const bf16x8*)&As[(wm + mt * 16 + lr) * BK + kt * 32 + quad * 8];
#pragma unroll
      for (int nt = 0; nt < 4; ++nt) bfr[nt] = *(const bf16x8*)&Bs[(wn + nt * 16 + lr) * BK + kt * 32 + quad * 8];
#pragma unroll
      for (int mt = 0; mt < 4; ++mt)
#pragma unroll
        for (int nt = 0; nt < 4; ++nt)
          acc[mt][nt] = __builtin_amdgcn_mfma_f32_16x16x32_bf16(af[mt], bfr[nt], acc[mt][nt], 0, 0, 0);
    }
    __syncthreads();
  }
  int row0 = bm * 128 + wm + quad * 4;
  int col0 = bn * 128 + wn + lr;
#pragma unroll
  for (int mt = 0; mt < 4; ++mt)
#pragma unroll
    for (int nt = 0; nt < 4; ++nt) {
      int col = col0 + nt * 16;
      float bv = bias[col];
#pragma unroll
      for (int r = 0; r < 4; ++r) {
        size_t idx = (size_t)(row0 + mt * 16 + r) * N + col;
        float v = acc[mt][nt][r] + bv;
        if (MODE == 0) ((bf16*)outp)[idx] = (bf16)fmaxf(v, 0.f);
        else if (MODE == 1) ((float*)outp)[idx] = v + res[idx];
        else ((float*)outp)[idx] = v;
      }
    }
}

// ---------------------------------------------------------------- launch
extern "C" void kernel_launch(void* const* d_in, const int* in_sizes, int n_in,
                              void* d_out, int out_size, void* d_ws, size_t ws_size,
                              hipStream_t stream) {
  const float* batch   = (const float*)d_in[0];
  const float* W_patch = (const float*)d_in[1];
  const float* b_patch = (const float*)d_in[2];
  const float* pos     = (const float*)d_in[3];
  const float* ln1_g   = (const float*)d_in[4];
  const float* ln1_b   = (const float*)d_in[5];
  const float* Wq      = (const float*)d_in[6];
  const float* bq      = (const float*)d_in[7];
  const float* Wk      = (const float*)d_in[8];
  const float* bk      = (const float*)d_in[9];
  const float* Wv      = (const float*)d_in[10];
  const float* bv      = (const float*)d_in[11];
  const float* ln2_g   = (const float*)d_in[12];
  const float* ln2_b   = (const float*)d_in[13];
  const float* W1      = (const float*)d_in[14];
  const float* b1      = (const float*)d_in[15];
  const float* W2      = (const float*)d_in[16];
  const float* b2      = (const float*)d_in[17];
  const float* W_out   = (const float*)d_in[18];
  const float* b_out   = (const float*)d_in[19];
  float* out = (float*)d_out;

  char* ws = (char*)d_ws;
  size_t off = 0;
  float* z     = (float*)(ws + off); off += (size_t)M * D * 4;        // 169,869,312
  float* stats = (float*)(ws + off); off += (size_t)M * 2 * 4;        // 442,368
  bf16* wq_b = (bf16*)(ws + off);    off += (size_t)4 * H * 4096 * 2;
  bf16* wk_b = (bf16*)(ws + off);    off += (size_t)4 * H * 4096 * 2;
  bf16* wv_b = (bf16*)(ws + off);    off += (size_t)4 * H * 4096 * 2;
  bf16* w1_b = (bf16*)(ws + off);    off += (size_t)4 * DFF * D * 2;
  bf16* w2_b = (bf16*)(ws + off);    off += (size_t)4 * D * DFF * 2;
  bf16* wo_b = (bf16*)(ws + off);    off += (size_t)OUTD * D * 2;
  bf16* act  = (bf16*)(ws + off);    // remainder, chunked

  size_t avail = ws_size > off ? ws_size - off : (size_t)0;
  long long rcl = (long long)(avail / ((size_t)DFF * 2));
  int rc = (rcl > (long long)M) ? M : (int)rcl;
  rc = (rc / 128) * 128;
  if (rc <= 0) rc = 128;

  f2b_kernel<<<192, 256, 0, stream>>>(Wq, wq_b, 49152);
  f2b_kernel<<<192, 256, 0, stream>>>(Wk, wk_b, 49152);
  f2b_kernel<<<192, 256, 0, stream>>>(Wv, wv_b, 49152);
  f2b_kernel<<<4608, 256, 0, stream>>>(W1, w1_b, 1179648);
  f2b_kernel<<<4608, 256, 0, stream>>>(W2, w2_b, 1179648);
  f2b_kernel<<<192, 256, 0, stream>>>(W_out, wo_b, 49152);

  patch_embed<<<BC, 256, 0, stream>>>(batch, W_patch, b_patch, pos, z);

  for (int l = 0; l < 4; ++l) {
    ln_stats<<<M / 4, 256, 0, stream>>>(z, stats);                       // LN1 stats
    attn_kernel<<<dim3(H, BC), 64, 0, stream>>>(z, stats, ln1_g + l * D, ln1_b + l * D,
        wq_b + (size_t)l * H * 4096, wk_b + (size_t)l * H * 4096, wv_b + (size_t)l * H * 4096,
        bq + l * H * 64, bk + l * H * 64, bv + l * H * 64, z);
    ln_inplace<<<M / 4, 256, 0, stream>>>(z, ln2_g + l * D, ln2_b + l * D);
    for (int m0 = 0; m0 < M; m0 += rc) {
      int mr = (M - m0 < rc) ? (M - m0) : rc;
      gemm_bt<DFF, D, 0, 1><<<dim3(DFF / 128, mr / 128), 256, 0, stream>>>(
          z + (size_t)m0 * D, w1_b + (size_t)l * DFF * D, b1 + l * DFF, nullptr, act);
      gemm_bt<D, DFF, 1, 0><<<dim3(D / 128, mr / 128), 256, 0, stream>>>(
          act, w2_b + (size_t)l * D * DFF, b2 + l * D, z + (size_t)m0 * D, z + (size_t)m0 * D);
    }
  }

  gemm_bt<OUTD, D, 2, 1><<<dim3(OUTD / 128, M / 128), 256, 0, stream>>>(
      z, wo_b, b_out, nullptr, out);
}

// Round 6
// 3498.276 us; speedup vs baseline: 1.2133x; 1.1488x over previous
//
#include <hip/hip_runtime.h>
#include <hip/hip_bf16.h>
#include <cstdint>
#include <cstddef>

typedef __bf16 bf16;
typedef bf16 bf16x8 __attribute__((ext_vector_type(8)));
typedef bf16 bf16x4 __attribute__((ext_vector_type(4)));
typedef float f32x4 __attribute__((ext_vector_type(4)));
typedef unsigned int u32;

#define GLD_LDS16(gptr, lptr)                                                        \
  __builtin_amdgcn_global_load_lds((const __attribute__((address_space(1))) u32*)(gptr), \
                                   (__attribute__((address_space(3))) u32*)(lptr), 16, 0, 0)

static constexpr int S = 36, D = 768, H = 12, HD = 64, DFF = 1536;
static constexpr int BC = 1536;        // B*C images
static constexpr int M = BC * S;       // 55296 tokens
static constexpr int OUTD = 256;

// ---------------------------------------------------------------- fp32 -> bf16
__global__ __launch_bounds__(256) void f2b_kernel(const float* __restrict__ in,
                                                  bf16* __restrict__ out, int n4) {
  int i = blockIdx.x * 256 + threadIdx.x;
  if (i < n4) {
    float4 f = ((const float4*)in)[i];
    bf16x4 o = {(bf16)f.x, (bf16)f.y, (bf16)f.z, (bf16)f.w};
    ((bf16x4*)out)[i] = o;
  }
}

// ---------------------------------------------------------------- patch embed
// one block per image; patch in LDS (broadcast reads), Wp row in registers.
__global__ __launch_bounds__(256) void patch_embed(const float* __restrict__ batch,
                                                   const float* __restrict__ Wp,
                                                   const float* __restrict__ bp,
                                                   const float* __restrict__ pos,
                                                   float* __restrict__ z) {
  int bc = blockIdx.x, tid = threadIdx.x;
  __shared__ float p[36][40];          // [token][pixel], padded row
  for (int i = tid; i < 1296; i += 256) {
    float f = batch[(size_t)bc * 1296 + i];
    int row = i / 36, col = i - row * 36;
    p[(row / 6) * 6 + col / 6][(row % 6) * 6 + (col % 6)] = f;
  }
  __syncthreads();
  for (int c0 = 0; c0 < 768; c0 += 256) {
    int d = c0 + tid;
    float wr[36];
    const float4* wp4 = (const float4*)(Wp + (size_t)d * 36);   // 144B rows, 16B aligned
#pragma unroll
    for (int q = 0; q < 9; ++q) {
      float4 f = wp4[q];
      wr[q * 4] = f.x; wr[q * 4 + 1] = f.y; wr[q * 4 + 2] = f.z; wr[q * 4 + 3] = f.w;
    }
    float gb = bp[d];
    for (int s = 0; s < 36; ++s) {
      float acc = 0.f;
#pragma unroll
      for (int k = 0; k < 36; ++k) acc += p[s][k] * wr[k];
      z[((size_t)bc * 36 + s) * 768 + d] = acc + gb + pos[s * 768 + d];
    }
  }
}

// ---------------------------------------------------------------- LN stats (mean, rstd) per row
__global__ __launch_bounds__(256) void ln_stats(const float* __restrict__ zin,
                                                float* __restrict__ stats) {
  int row = blockIdx.x * 4 + (threadIdx.x >> 6);
  int lane = threadIdx.x & 63;
  const float* zr = zin + (size_t)row * D;
  float x[12];
#pragma unroll
  for (int i = 0; i < 12; ++i) x[i] = zr[i * 64 + lane];
  float s = 0.f;
#pragma unroll
  for (int i = 0; i < 12; ++i) s += x[i];
#pragma unroll
  for (int off = 32; off >= 1; off >>= 1) s += __shfl_xor(s, off, 64);
  float m = s * (1.f / 768.f);
  float v = 0.f;
#pragma unroll
  for (int i = 0; i < 12; ++i) { float dd = x[i] - m; v += dd * dd; }
#pragma unroll
  for (int off = 32; off >= 1; off >>= 1) v += __shfl_xor(v, off, 64);
  v *= (1.f / 768.f);
  if (lane == 0) {
    stats[(size_t)row * 2] = m;
    stats[(size_t)row * 2 + 1] = rsqrtf(v + 1e-5f);
  }
}

// ---------------------------------------------------------------- LN in-place (fp32)
__global__ __launch_bounds__(256) void ln_inplace(float* __restrict__ z,
                                                  const float* __restrict__ g,
                                                  const float* __restrict__ bt) {
  int row = blockIdx.x * 4 + (threadIdx.x >> 6);
  int lane = threadIdx.x & 63;
  float* zr = z + (size_t)row * D;
  float x[12];
#pragma unroll
  for (int i = 0; i < 12; ++i) x[i] = zr[i * 64 + lane];
  float s = 0.f;
#pragma unroll
  for (int i = 0; i < 12; ++i) s += x[i];
#pragma unroll
  for (int off = 32; off >= 1; off >>= 1) s += __shfl_xor(s, off, 64);
  float m = s * (1.f / 768.f);
  float v = 0.f;
#pragma unroll
  for (int i = 0; i < 12; ++i) { float dd = x[i] - m; v += dd * dd; }
#pragma unroll
  for (int off = 32; off >= 1; off >>= 1) v += __shfl_xor(v, off, 64);
  v *= (1.f / 768.f);
  float rstd = rsqrtf(v + 1e-5f);
#pragma unroll
  for (int i = 0; i < 12; ++i) {
    int d = i * 64 + lane;
    zr[d] = (x[i] - m) * rstd * g[d] + bt[d];
  }
}

// ---------------------------------------------------------------- fused attention
// one wave per (head, image). Bit-equivalent restructure of the R5 kernel:
//  - A-fragments (LN1'd h) built in registers, rows>=36 explicitly ZERO
//    (identical to R5's zero-padded hbuf staging).
//  - qb/kb/vt strides 64 -> 72 (contents unchanged; 144B rows stay 16B-aligned,
//    vt transpose-write conflict 16-way -> 2-way(free), q/k/P writes 8 -> 4-way).
//  - P reuses qb after scores are in registers (single-wave block, no race).
// LDS 32768 -> 23040 B: 5 -> 7 blocks/CU.
__global__ __launch_bounds__(64) void attn_kernel(const float* __restrict__ zg,
                                                  const float* __restrict__ stats,
                                                  const float* __restrict__ g1,
                                                  const float* __restrict__ b1_,
                                                  const bf16* __restrict__ Wq,
                                                  const bf16* __restrict__ Wk,
                                                  const bf16* __restrict__ Wv,
                                                  const float* __restrict__ bq,
                                                  const float* __restrict__ bk,
                                                  const float* __restrict__ bv,
                                                  float* __restrict__ z) {
  int head = blockIdx.x;
  int bc = blockIdx.y;
  __shared__ __align__(16) bf16 qb[48 * 72];   // Q, later P
  __shared__ __align__(16) bf16 kb[48 * 72];
  __shared__ __align__(16) bf16 vt[64 * 72];   // vt[e][t]
  int lane = threadIdx.x;
  int lr = lane & 15, quad = lane >> 4;

  // zero vt pad cols [48,64)
#pragma unroll
  for (int t0 = 0; t0 < 16; ++t0) vt[lane * 72 + 48 + t0] = (bf16)0.f;

  const float* zsrc = zg + ((size_t)bc * S) * D + head * HD;
  const float* st = stats + (size_t)bc * S * 2;

  // per-lane LN gamma/beta for fragment columns: col = kt*32 + quad*8 + j
  float gv[2][8], bvv[2][8];
#pragma unroll
  for (int kt = 0; kt < 2; ++kt) {
    int c0 = head * HD + kt * 32 + quad * 8;
    float4 ga = *(const float4*)(g1 + c0);
    float4 gb2 = *(const float4*)(g1 + c0 + 4);
    float4 ba = *(const float4*)(b1_ + c0);
    float4 bb2 = *(const float4*)(b1_ + c0 + 4);
    gv[kt][0] = ga.x; gv[kt][1] = ga.y; gv[kt][2] = ga.z; gv[kt][3] = ga.w;
    gv[kt][4] = gb2.x; gv[kt][5] = gb2.y; gv[kt][6] = gb2.z; gv[kt][7] = gb2.w;
    bvv[kt][0] = ba.x; bvv[kt][1] = ba.y; bvv[kt][2] = ba.z; bvv[kt][3] = ba.w;
    bvv[kt][4] = bb2.x; bvv[kt][5] = bb2.y; bvv[kt][6] = bb2.z; bvv[kt][7] = bb2.w;
  }

  // A-fragments of LN1(h): row = mt*16+lr (zero for rows >= 36)
  bf16x8 hfrag[3][2];
#pragma unroll
  for (int mt = 0; mt < 3; ++mt) {
    int srow = mt * 16 + lr;
    if (srow < 36) {
      float mm = st[srow * 2], rr = st[srow * 2 + 1];
#pragma unroll
      for (int kt = 0; kt < 2; ++kt) {
        int c0 = kt * 32 + quad * 8;
        float4 f0 = *(const float4*)(zsrc + (size_t)srow * D + c0);
        float4 f1 = *(const float4*)(zsrc + (size_t)srow * D + c0 + 4);
        float hv[8] = {f0.x, f0.y, f0.z, f0.w, f1.x, f1.y, f1.z, f1.w};
        bf16x8 o;
#pragma unroll
        for (int j = 0; j < 8; ++j) o[j] = (bf16)((hv[j] - mm) * rr * gv[kt][j] + bvv[kt][j]);
        hfrag[mt][kt] = o;
      }
    } else {
#pragma unroll
      for (int kt = 0; kt < 2; ++kt) {
        bf16x8 o;
#pragma unroll
        for (int j = 0; j < 8; ++j) o[j] = (bf16)0.f;
        hfrag[mt][kt] = o;
      }
    }
  }

  // ---- projections q,k,v
  const bf16* Wm[3] = {Wq + (size_t)head * 4096, Wk + (size_t)head * 4096, Wv + (size_t)head * 4096};
  const float* Bm[3] = {bq + head * 64, bk + head * 64, bv + head * 64};
  for (int p = 0; p < 3; ++p) {
    bf16x8 bfr[4][2];
#pragma unroll
    for (int nt = 0; nt < 4; ++nt)
#pragma unroll
      for (int kt = 0; kt < 2; ++kt)
        bfr[nt][kt] = *(const bf16x8*)(Wm[p] + (nt * 16 + lr) * 64 + kt * 32 + quad * 8);
#pragma unroll
    for (int mt = 0; mt < 3; ++mt) {
      f32x4 acc[4] = {};
#pragma unroll
      for (int kt = 0; kt < 2; ++kt)
#pragma unroll
        for (int nt = 0; nt < 4; ++nt)
          acc[nt] = __builtin_amdgcn_mfma_f32_16x16x32_bf16(hfrag[mt][kt], bfr[nt][kt], acc[nt], 0, 0, 0);
#pragma unroll
      for (int nt = 0; nt < 4; ++nt) {
        float bb = Bm[p][nt * 16 + lr];
#pragma unroll
        for (int r = 0; r < 4; ++r) {
          int s2 = mt * 16 + quad * 4 + r;
          int e = nt * 16 + lr;
          float val = acc[nt][r] + bb;
          if (p == 0) qb[s2 * 72 + e] = (bf16)val;
          else if (p == 1) kb[s2 * 72 + e] = (bf16)val;
          else vt[e * 72 + s2] = (bf16)val;
        }
      }
    }
  }
  __syncthreads();

  // ---- scores (into registers)
  f32x4 sc[3][3];
#pragma unroll
  for (int mt = 0; mt < 3; ++mt)
#pragma unroll
    for (int nt = 0; nt < 3; ++nt) {
      f32x4 a = {};
#pragma unroll
      for (int kt = 0; kt < 2; ++kt) {
        bf16x8 af = *(const bf16x8*)&qb[(mt * 16 + lr) * 72 + kt * 32 + quad * 8];
        bf16x8 bf_ = *(const bf16x8*)&kb[(nt * 16 + lr) * 72 + kt * 32 + quad * 8];
        a = __builtin_amdgcn_mfma_f32_16x16x32_bf16(af, bf_, a, 0, 0, 0);
      }
      int t = nt * 16 + lr;
#pragma unroll
      for (int r = 0; r < 4; ++r) {
        float v = a[r] * 0.125f;     // 1/sqrt(64)
        if (t >= 36) v = -1e30f;
        sc[mt][nt][r] = v;
      }
    }
  __syncthreads();

  // ---- softmax; write P into qb (reuse; single-wave block)
#pragma unroll
  for (int mt = 0; mt < 3; ++mt) {
    float mx[4], sum[4];
#pragma unroll
    for (int r = 0; r < 4; ++r)
      mx[r] = fmaxf(fmaxf(sc[mt][0][r], sc[mt][1][r]), sc[mt][2][r]);
#pragma unroll
    for (int r = 0; r < 4; ++r)
#pragma unroll
      for (int off = 8; off >= 1; off >>= 1) mx[r] = fmaxf(mx[r], __shfl_xor(mx[r], off, 64));
#pragma unroll
    for (int r = 0; r < 4; ++r) sum[r] = 0.f;
#pragma unroll
    for (int nt = 0; nt < 3; ++nt)
#pragma unroll
      for (int r = 0; r < 4; ++r) {
        float e = __expf(sc[mt][nt][r] - mx[r]);
        sc[mt][nt][r] = e;
        sum[r] += e;
      }
#pragma unroll
    for (int r = 0; r < 4; ++r)
#pragma unroll
      for (int off = 8; off >= 1; off >>= 1) sum[r] += __shfl_xor(sum[r], off, 64);
#pragma unroll
    for (int nt = 0; nt < 4; ++nt)
#pragma unroll
      for (int r = 0; r < 4; ++r) {
        int s2 = mt * 16 + quad * 4 + r;
        int t = nt * 16 + lr;
        float pv = (nt < 3) ? sc[mt][nt][r] / sum[r] : 0.f;
        qb[s2 * 72 + t] = (bf16)pv;
      }
  }
  __syncthreads();

  // ---- o = P @ V, z += o
#pragma unroll
  for (int mt = 0; mt < 3; ++mt) {
    f32x4 o[4] = {};
#pragma unroll
    for (int kt = 0; kt < 2; ++kt) {
      bf16x8 a = *(const bf16x8*)&qb[(mt * 16 + lr) * 72 + kt * 32 + quad * 8];
#pragma unroll
      for (int nt = 0; nt < 4; ++nt) {
        bf16x8 b = *(const bf16x8*)&vt[(nt * 16 + lr) * 72 + kt * 32 + quad * 8];
        o[nt] = __builtin_amdgcn_mfma_f32_16x16x32_bf16(a, b, o[nt], 0, 0, 0);
      }
    }
#pragma unroll
    for (int nt = 0; nt < 4; ++nt)
#pragma unroll
      for (int r = 0; r < 4; ++r) {
        int s2 = mt * 16 + quad * 4 + r;
        if (s2 < 36) {
          int e = nt * 16 + lr;
          size_t idx = ((size_t)bc * S + s2) * D + head * HD + e;
          z[idx] += o[nt][r];
        }
      }
  }
}

// ---------------------------------------------------------------- GEMM (B^T layout)
// C[m,n] = sum_k A[m,k]*B[n,k]
// MODE 0: bf16 out = relu(.+bias); MODE 1: f32 out = .+bias+res; MODE 2: f32 out = .+bias
// AF32 1: A is fp32, staged via VGPR+convert; 0: A bf16 via global_load_lds
template <int N, int K, int MODE, int AF32>
__global__ __launch_bounds__(256) void gemm_bt(const void* __restrict__ A,
                                               const bf16* __restrict__ Bw,
                                               const float* __restrict__ bias,
                                               const float* __restrict__ res,
                                               void* __restrict__ outp) {
  constexpr int BK = 64;
  __shared__ __align__(16) bf16 As[128 * BK];
  __shared__ __align__(16) bf16 Bs[128 * BK];
  int tid = threadIdx.x;
  int bn = blockIdx.x, bm = blockIdx.y;
  const bf16* Abf = (const bf16*)A + (size_t)bm * 128 * K;
  const float* Af = (const float*)A + (size_t)bm * 128 * K;
  const bf16* Bb = Bw + (size_t)bn * 128 * K;
  int lane = tid & 63, wave = tid >> 6;
  int wm = (wave >> 1) * 64, wn = (wave & 1) * 64;
  int lr = lane & 15, quad = lane >> 4;
  f32x4 acc[4][4] = {};
  for (int k0 = 0; k0 < K; k0 += BK) {
    if (AF32) {
#pragma unroll
      for (int r = 0; r < 8; ++r) {
        int c = r * 256 + tid;            // 0..2047 float4-units
        int row = c >> 4, col4 = (c & 15) * 4;
        float4 f = *(const float4*)(Af + (size_t)row * K + k0 + col4);
        bf16x4 o = {(bf16)f.x, (bf16)f.y, (bf16)f.z, (bf16)f.w};
        *(bf16x4*)&As[row * BK + col4] = o;
      }
    } else {
#pragma unroll
      for (int r = 0; r < 4; ++r) {
        int c = r * 256 + tid;
        int row = c >> 3, col = (c & 7) * 8;
        GLD_LDS16(Abf + (size_t)row * K + k0 + col, &As[c * 8]);
      }
    }
#pragma unroll
    for (int r = 0; r < 4; ++r) {
      int c = r * 256 + tid;
      int row = c >> 3, col = (c & 7) * 8;
      GLD_LDS16(Bb + (size_t)row * K + k0 + col, &Bs[c * 8]);
    }
    __syncthreads();
#pragma unroll
    for (int kt = 0; kt < 2; ++kt) {
      bf16x8 af[4], bfr[4];
#pragma unroll
      for (int mt = 0; mt < 4; ++mt) af[mt] = *(const bf16x8*)&As[(wm + mt * 16 + lr) * BK + kt * 32 + quad * 8];
#pragma unroll
      for (int nt = 0; nt < 4; ++nt) bfr[nt] = *(const bf16x8*)&Bs[(wn + nt * 16 + lr) * BK + kt * 32 + quad * 8];
#pragma unroll
      for (int mt = 0; mt < 4; ++mt)
#pragma unroll
        for (int nt = 0; nt < 4; ++nt)
          acc[mt][nt] = __builtin_amdgcn_mfma_f32_16x16x32_bf16(af[mt], bfr[nt], acc[mt][nt], 0, 0, 0);
    }
    __syncthreads();
  }
  int row0 = bm * 128 + wm + quad * 4;
  int col0 = bn * 128 + wn + lr;
#pragma unroll
  for (int mt = 0; mt < 4; ++mt)
#pragma unroll
    for (int nt = 0; nt < 4; ++nt) {
      int col = col0 + nt * 16;
      float bv = bias[col];
#pragma unroll
      for (int r = 0; r < 4; ++r) {
        size_t idx = (size_t)(row0 + mt * 16 + r) * N + col;
        float v = acc[mt][nt][r] + bv;
        if (MODE == 0) ((bf16*)outp)[idx] = (bf16)fmaxf(v, 0.f);
        else if (MODE == 1) ((float*)outp)[idx] = v + res[idx];
        else ((float*)outp)[idx] = v;
      }
    }
}

// ---------------------------------------------------------------- launch
extern "C" void kernel_launch(void* const* d_in, const int* in_sizes, int n_in,
                              void* d_out, int out_size, void* d_ws, size_t ws_size,
                              hipStream_t stream) {
  const float* batch   = (const float*)d_in[0];
  const float* W_patch = (const float*)d_in[1];
  const float* b_patch = (const float*)d_in[2];
  const float* pos     = (const float*)d_in[3];
  const float* ln1_g   = (const float*)d_in[4];
  const float* ln1_b   = (const float*)d_in[5];
  const float* Wq      = (const float*)d_in[6];
  const float* bq      = (const float*)d_in[7];
  const float* Wk      = (const float*)d_in[8];
  const float* bk      = (const float*)d_in[9];
  const float* Wv      = (const float*)d_in[10];
  const float* bv      = (const float*)d_in[11];
  const float* ln2_g   = (const float*)d_in[12];
  const float* ln2_b   = (const float*)d_in[13];
  const float* W1      = (const float*)d_in[14];
  const float* b1      = (const float*)d_in[15];
  const float* W2      = (const float*)d_in[16];
  const float* b2      = (const float*)d_in[17];
  const float* W_out   = (const float*)d_in[18];
  const float* b_out   = (const float*)d_in[19];
  float* out = (float*)d_out;

  char* ws = (char*)d_ws;
  size_t off = 0;
  float* z     = (float*)(ws + off); off += (size_t)M * D * 4;        // 169,869,312
  float* stats = (float*)(ws + off); off += (size_t)M * 2 * 4;        // 442,368
  bf16* wq_b = (bf16*)(ws + off);    off += (size_t)4 * H * 4096 * 2;
  bf16* wk_b = (bf16*)(ws + off);    off += (size_t)4 * H * 4096 * 2;
  bf16* wv_b = (bf16*)(ws + off);    off += (size_t)4 * H * 4096 * 2;
  bf16* w1_b = (bf16*)(ws + off);    off += (size_t)4 * DFF * D * 2;
  bf16* w2_b = (bf16*)(ws + off);    off += (size_t)4 * D * DFF * 2;
  bf16* wo_b = (bf16*)(ws + off);    off += (size_t)OUTD * D * 2;
  bf16* act  = (bf16*)(ws + off);    // remainder, chunked

  size_t avail = ws_size > off ? ws_size - off : (size_t)0;
  long long rcl = (long long)(avail / ((size_t)DFF * 2));
  int rc = (rcl > (long long)M) ? M : (int)rcl;
  rc = (rc / 128) * 128;
  if (rc <= 0) rc = 128;

  f2b_kernel<<<192, 256, 0, stream>>>(Wq, wq_b, 49152);
  f2b_kernel<<<192, 256, 0, stream>>>(Wk, wk_b, 49152);
  f2b_kernel<<<192, 256, 0, stream>>>(Wv, wv_b, 49152);
  f2b_kernel<<<4608, 256, 0, stream>>>(W1, w1_b, 1179648);
  f2b_kernel<<<4608, 256, 0, stream>>>(W2, w2_b, 1179648);
  f2b_kernel<<<192, 256, 0, stream>>>(W_out, wo_b, 49152);

  patch_embed<<<BC, 256, 0, stream>>>(batch, W_patch, b_patch, pos, z);

  for (int l = 0; l < 4; ++l) {
    ln_stats<<<M / 4, 256, 0, stream>>>(z, stats);                       // LN1 stats
    attn_kernel<<<dim3(H, BC), 64, 0, stream>>>(z, stats, ln1_g + l * D, ln1_b + l * D,
        wq_b + (size_t)l * H * 4096, wk_b + (size_t)l * H * 4096, wv_b + (size_t)l * H * 4096,
        bq + l * H * 64, bk + l * H * 64, bv + l * H * 64, z);
    ln_inplace<<<M / 4, 256, 0, stream>>>(z, ln2_g + l * D, ln2_b + l * D);
    for (int m0 = 0; m0 < M; m0 += rc) {
      int mr = (M - m0 < rc) ? (M - m0) : rc;
      gemm_bt<DFF, D, 0, 1><<<dim3(DFF / 128, mr / 128), 256, 0, stream>>>(
          z + (size_t)m0 * D, w1_b + (size_t)l * DFF * D, b1 + l * DFF, nullptr, act);
      gemm_bt<D, DFF, 1, 0><<<dim3(D / 128, mr / 128), 256, 0, stream>>>(
          act, w2_b + (size_t)l * D * DFF, b2 + l * D, z + (size_t)m0 * D, z + (size_t)m0 * D);
    }
  }

  gemm_bt<OUTD, D, 2, 1><<<dim3(OUTD / 128, M / 128), 256, 0, stream>>>(
      z, wo_b, b_out, nullptr, out);
}